// Round 10
// baseline (3006.621 us; speedup 1.0000x reference)
//
#include <hip/hip_runtime.h>

typedef unsigned short u16;
typedef unsigned int   u32;
typedef __attribute__((ext_vector_type(4))) u16   u16x4;
typedef __attribute__((ext_vector_type(8))) u16   u16x8;
typedef __attribute__((ext_vector_type(8))) __bf16 bf16x8;
typedef __attribute__((ext_vector_type(4))) float  floatx4;
typedef __attribute__((ext_vector_type(4))) u32   u32x4;

#define TT 512   // seq len
#define BB 64    // batch
#define HD 512   // hidden/emb dim
#define SENT 0xAAAAAAAAu

// ---------- helpers ----------
__device__ __forceinline__ u16 f2bf(float f) {
  u32 u = __builtin_bit_cast(u32, f);
  u32 r = u + 0x7fffu + ((u >> 16) & 1u);   // round-to-nearest-even
  return (u16)(r >> 16);
}
__device__ __forceinline__ float bf2f(u16 h) {
  return __builtin_bit_cast(float, ((u32)h) << 16);
}
__device__ __forceinline__ float fast_tanh(float x) {
  float xc = fminf(fmaxf(x, -12.f), 12.f);
  float e = __expf(2.f * xc);
  return __fdividef(e - 1.f, e + 1.f);
}
__device__ __forceinline__ u32 aload(const u32* p) {
  return __hip_atomic_load(p, __ATOMIC_RELAXED, __HIP_MEMORY_SCOPE_AGENT);
}
__device__ __forceinline__ void astore(u32* p, u32 v) {
  __hip_atomic_store(p, v, __ATOMIC_RELAXED, __HIP_MEMORY_SCOPE_AGENT);
}

// ---------- prep: convert 3 weight matrices to bf16, sum biases ----------
// wbf3 layout: [whh0 | wih1 | whh1], each 512*512
__global__ __launch_bounds__(256)
void prep_kernel(const float* __restrict__ W_ih, const float* __restrict__ W_hh,
                 const float* __restrict__ b_ih, const float* __restrict__ b_hh,
                 u16* __restrict__ wbf3, float* __restrict__ bsum) {
  int idx = blockIdx.x * blockDim.x + threadIdx.x;
  int stride = gridDim.x * blockDim.x;
  for (int i = idx; i < 3 * 262144; i += stride) {
    int mat = i >> 18;
    int off = i & 262143;
    const float* src = (mat == 0) ? W_hh : (mat == 1) ? (W_ih + 262144)
                                         : (W_hh + 262144);
    wbf3[i] = f2bf(src[off]);
  }
  if (idx < 1024) bsum[idx] = b_ih[idx] + b_hh[idx];
}

// ---------- pre-activation GEMM ----------
// Xpre[m][n] = A[m][:] @ W[n][:] + bsum[n],  M=T*B (m = t*64+b), K=N=512
// Weights BwF fp32 (converted to bf16 on the fly).
// mode 0: A row = emb[x[b][t]]; mode 1: A row = hist[t+1][b] lo16 (fallback)
__global__ __launch_bounds__(256, 2)
void gemm_pre(const float* __restrict__ BwF, const float* __restrict__ bsum,
              const float* __restrict__ embsrc, const int* __restrict__ xtok,
              const u32* __restrict__ hist, float* __restrict__ Xpre, int mode) {
  __shared__ u16 As[128][40];
  __shared__ u16 Bs[128][40];
  const int tid = threadIdx.x;
  const int wave = tid >> 6, lane = tid & 63;
  const int quad = lane >> 4, l16 = lane & 15;
  const int mtile = blockIdx.x >> 2, ntile = blockIdx.x & 3;
  const int m0 = mtile * 128, n0 = ntile * 128;
  const int srow = tid >> 1, half = tid & 1;

  const float* aF = nullptr; const u32* aU = nullptr;
  {
    const int grow = m0 + srow;
    if (mode == 0) {
      const int t = grow >> 6, b = grow & 63;
      const int tok = xtok[b * TT + t];
      aF = embsrc + (size_t)tok * 512 + half * 16;
    } else {
      aU = hist + (size_t)((grow >> 6) + 1) * 32768 + (size_t)(grow & 63) * 512 + half * 16;
    }
  }
  const float* bptrF = BwF + (size_t)(n0 + srow) * 512 + half * 16;

  floatx4 acc[2][8];
#pragma unroll
  for (int a = 0; a < 2; a++)
#pragma unroll
    for (int b = 0; b < 8; b++) acc[a][b] = (floatx4){0.f, 0.f, 0.f, 0.f};

  for (int ks = 0; ks < 16; ks++) {
    const int k0 = ks * 32;
    u32 packed[8];
    if (mode == 0) {
      const float4* p = (const float4*)(aF + k0);
      float4 f0 = p[0], f1 = p[1], f2 = p[2], f3 = p[3];
      float vals[16] = {f0.x, f0.y, f0.z, f0.w, f1.x, f1.y, f1.z, f1.w,
                        f2.x, f2.y, f2.z, f2.w, f3.x, f3.y, f3.z, f3.w};
#pragma unroll
      for (int j = 0; j < 8; j++)
        packed[j] = (u32)f2bf(vals[2 * j]) | ((u32)f2bf(vals[2 * j + 1]) << 16);
    } else {
      const u32x4* p = (const u32x4*)(aU + k0);
      u32x4 q0 = p[0], q1 = p[1], q2 = p[2], q3 = p[3];
      u32 w[16] = {q0[0], q0[1], q0[2], q0[3], q1[0], q1[1], q1[2], q1[3],
                   q2[0], q2[1], q2[2], q2[3], q3[0], q3[1], q3[2], q3[3]};
#pragma unroll
      for (int j = 0; j < 8; j++)
        packed[j] = (w[2 * j] & 0xffffu) | ((w[2 * j + 1] & 0xffffu) << 16);
    }
    {
      u32x4* adst = (u32x4*)&As[srow][half * 16];
      adst[0] = (u32x4){packed[0], packed[1], packed[2], packed[3]};
      adst[1] = (u32x4){packed[4], packed[5], packed[6], packed[7]};
    }
    {
      const float4* bp = (const float4*)(bptrF + k0);
      float4 f0 = bp[0], f1 = bp[1], f2 = bp[2], f3 = bp[3];
      float vals[16] = {f0.x, f0.y, f0.z, f0.w, f1.x, f1.y, f1.z, f1.w,
                        f2.x, f2.y, f2.z, f2.w, f3.x, f3.y, f3.z, f3.w};
      u32 bpk[8];
#pragma unroll
      for (int j = 0; j < 8; j++)
        bpk[j] = (u32)f2bf(vals[2 * j]) | ((u32)f2bf(vals[2 * j + 1]) << 16);
      u32x4* bdst = (u32x4*)&Bs[srow][half * 16];
      bdst[0] = (u32x4){bpk[0], bpk[1], bpk[2], bpk[3]};
      bdst[1] = (u32x4){bpk[4], bpk[5], bpk[6], bpk[7]};
    }
    __syncthreads();
    bf16x8 afr[2], bfr[8];
#pragma unroll
    for (int mt = 0; mt < 2; mt++)
      afr[mt] = __builtin_bit_cast(bf16x8, *(const u16x8*)&As[wave * 32 + mt * 16 + l16][quad * 8]);
#pragma unroll
    for (int nt = 0; nt < 8; nt++)
      bfr[nt] = __builtin_bit_cast(bf16x8, *(const u16x8*)&Bs[nt * 16 + l16][quad * 8]);
#pragma unroll
    for (int mt = 0; mt < 2; mt++)
#pragma unroll
      for (int nt = 0; nt < 8; nt++)
        acc[mt][nt] = __builtin_amdgcn_mfma_f32_16x16x32_bf16(afr[mt], bfr[nt], acc[mt][nt], 0, 0, 0);
    __syncthreads();
  }
  float bs[8];
#pragma unroll
  for (int nt = 0; nt < 8; nt++) bs[nt] = bsum[n0 + nt * 16 + l16];
#pragma unroll
  for (int mt = 0; mt < 2; mt++)
#pragma unroll
    for (int nt = 0; nt < 8; nt++)
#pragma unroll
      for (int i = 0; i < 4; i++) {
        const int gm = m0 + wave * 32 + mt * 16 + quad * 4 + i;
        Xpre[(size_t)gm * 512 + n0 + nt * 16 + l16] = acc[mt][nt][i] + bs[nt];
      }
}

// ---------- FUSED pipeline, 64 WGs x 512 threads ----------
// role 0 (bid 0..31) MERGED layer-0 + pre1 producer:
//   all 8 waves poll+stage h0(t-1) from hist0[t] (2 rows/wave, sentinel);
//   waves 0-3 (Whh0 in regs): h0(t)=tanh(Xpre(t)+h0(t-1)@Whh0^T) -> hist0[t+1]
//   waves 4-7 (Wih1 in regs): pre1(t-1)=h0(t-1)@Wih1^T+b1 -> pre1 (SENT bump)
//   One staging + one barrier serves BOTH matmuls (role-1 of R4 deleted:
//   its poll/fetch of the same slab was pure duplicated LLC traffic).
//   Loop runs TT+1 iterations (last one produces pre1(TT-1) only).
// role 1 (bid 32..63) layer-1 recurrence, R4-verbatim (waves 0-3; waves 4-7
//   only match the per-step barrier):
//   polls pre1(t) (4 wds, SENT) + h1(t-1) depth-4 tag ring; publishes ring.
__global__ __launch_bounds__(512, 1)
void rnn_fused2(const u16* __restrict__ wbf3, const float* __restrict__ bsum,
                const float* __restrict__ Xpre,
                u32* __restrict__ hist0, u32* __restrict__ pre1,
                u32* __restrict__ ring1,
                const int* __restrict__ lengths, float* __restrict__ out) {
  __shared__ u32 lds[16384];   // 64 KiB: [2][16][512] double-buffered staging
  u32 (*Ab)[16][512] = reinterpret_cast<u32 (*)[16][512]>(lds);
  const int tid = threadIdx.x;
  const int wave = tid >> 6, lane = tid & 63;
  const int quad = lane >> 4, l16 = lane & 15;
  const int bid = blockIdx.x;
  const int role = bid >> 5;
  const int sub = bid & 31;
  const int c = sub >> 2, g = sub & 3;
  const int xswr = (l16 & 7) << 2;

  if (role == 0) {
    // ================= merged layer-0 + pre1 producer =================
    const bool isH = (wave < 4);
    const int cw = wave & 3;                       // column-wave 0..3
    const int mycol = c * 64 + cw * 16 + l16;
    const int r2 = wave * 2;                       // this wave's 2 staging rows

    bf16x8 wfrag[32];
    {
      const u16* W = isH ? wbf3 /*whh0*/ : (wbf3 + 262144) /*wih1*/;
      const u16* wrow = W + (size_t)mycol * 512 + quad * 4;
#pragma unroll
      for (int s = 0; s < 32; s++) {
        u16x4 w4v = *(const u16x4*)(wrow + s * 16);
        u16x8 w8 = {w4v[0], w4v[0], w4v[1], w4v[1], w4v[2], w4v[2], w4v[3], w4v[3]};
        wfrag[s] = __builtin_bit_cast(bf16x8, w8);
      }
    }
    float hcur[4];
    int lens[4];
    float bs1 = 0.f;
    if (isH) {
#pragma unroll
      for (int i = 0; i < 4; i++) {
        hcur[i] = 0.f;
        lens[i] = lengths[g * 16 + quad * 4 + i];
      }
    } else {
      bs1 = bsum[512 + mycol];
    }

    for (int t = 0; t <= TT; t++) {
      const int buf = t & 1;
      float pre[4];
      if (isH && t < TT) {
#pragma unroll
        for (int i = 0; i < 4; i++)
          pre[i] = Xpre[(size_t)t * 32768 + (size_t)(g * 16 + quad * 4 + i) * 512 + mycol];
      }
      // ---- poll + stage h0(t-1): 2 rows per wave, 16 words per thread
      u32 v[16];
      const u32* sbase = hist0 + (size_t)t * 32768 + (size_t)(g * 16 + r2) * 512 + lane;
#pragma unroll
      for (int j = 0; j < 16; j++)
        v[j] = aload(sbase + (j >> 3) * 512 + (j & 7) * 64);
      {
        int guard = 0;
        while (true) {
          u32 pend = 0;
#pragma unroll
          for (int j = 0; j < 16; j++) pend |= (u32)(v[j] == SENT);
          if (__builtin_expect(pend == 0u, 1)) break;
          if (++guard > (1 << 16)) break;
          __builtin_amdgcn_s_sleep(1);
#pragma unroll
          for (int j = 0; j < 16; j++)
            v[j] = aload(sbase + (j >> 3) * 512 + (j & 7) * 64);
        }
      }
#pragma unroll
      for (int rr = 0; rr < 2; rr++) {
        const int row = r2 + rr;
        u32* wrow = &Ab[buf][row][0];
        const int xsw = (row & 7) << 2;
#pragma unroll
        for (int k = 0; k < 8; k++)
          wrow[(k * 64 + lane) ^ xsw] = v[rr * 8 + k];
      }
      __syncthreads();

      const bool doCompute = isH ? (t < TT) : (t >= 1);
      if (doCompute) {
        floatx4 ac[4];
#pragma unroll
        for (int q = 0; q < 4; q++) ac[q] = (floatx4){0.f, 0.f, 0.f, 0.f};
        const u32* arow = &Ab[buf][l16][0];
#pragma unroll
        for (int s = 0; s < 32; s += 4) {
#pragma unroll
          for (int q = 0; q < 4; q++) {
            bf16x8 a = __builtin_bit_cast(bf16x8,
                *(const u16x8*)(arow + (((s + q) * 16 + quad * 4) ^ xswr)));
            ac[q] = __builtin_amdgcn_mfma_f32_16x16x32_bf16(a, wfrag[s + q], ac[q], 0, 0, 0);
          }
        }
        if (isH) {
#pragma unroll
          for (int i = 0; i < 4; i++) {
            const float vsum = ac[0][i] + ac[1][i] + ac[2][i] + ac[3][i] + pre[i];
            const float th = fast_tanh(vsum);
            const float nv = (t < lens[i]) ? th : hcur[i];
            hcur[i] = nv;
            const u16 hi = f2bf(nv);
            const u16 lo = f2bf(nv - bf2f(hi));
            u32 wv = (u32)hi | ((u32)lo << 16);
            wv += (wv == SENT);
            astore(hist0 + (size_t)(t + 1) * 32768 +
                       (size_t)(g * 16 + quad * 4 + i) * 512 + mycol, wv);
          }
        } else {
#pragma unroll
          for (int i = 0; i < 4; i++) {
            const float pv = ac[0][i] + ac[1][i] + ac[2][i] + ac[3][i] + bs1;
            u32 b = __builtin_bit_cast(u32, pv);
            b += (b == SENT);   // exclude sentinel (1 ulp)
            astore(pre1 + (size_t)(t - 1) * 32768 +
                       (size_t)(g * 16 + quad * 4 + i) * 512 + mycol, b);
          }
        }
      }
    }
    if (isH) {
#pragma unroll
      for (int i = 0; i < 4; i++) {
        const int b = g * 16 + quad * 4 + i;
        out[32768 + (size_t)b * 1024 + mycol] = hcur[i];   // hidden[:,0,:]
      }
    }
  } else {
    // ================= layer 1 (R4-verbatim, waves 0-3) =================
    if (wave >= 4) {
      for (int t = 0; t < TT; t++) __syncthreads();   // match barriers
      return;
    }
    const int mycol = c * 64 + wave * 16 + l16;
    const int w4 = wave * 4;
    const u16* Whh = wbf3 + 524288;   // whh1
    bf16x8 wfh[32];
    {
      const u16* wrow = Whh + (size_t)mycol * 512 + quad * 4;
#pragma unroll
      for (int s = 0; s < 32; s++) {
        u16x4 w4v = *(const u16x4*)(wrow + s * 16);
        u16x8 w8 = {w4v[0], w4v[0], w4v[1], w4v[1], w4v[2], w4v[2], w4v[3], w4v[3]};
        wfh[s] = __builtin_bit_cast(bf16x8, w8);
      }
    }
    float hcur[4];
    int lens[4];
#pragma unroll
    for (int i = 0; i < 4; i++) {
      hcur[i] = 0.f;
      lens[i] = lengths[g * 16 + quad * 4 + i];
    }
    for (int t = 0; t < TT; t++) {
      const int buf = t & 1;
      const u32 etag = (u32)((t >> 2) & 1);
      u32 v[32], p[4];
      const u32* rb = ring1 + (size_t)(t & 3) * 32768 + (size_t)(g * 16 + w4) * 512 + lane;
      const u32* pb = pre1 + (size_t)t * 32768 + (size_t)(g * 16 + quad * 4) * 512 + mycol;
#pragma unroll
      for (int j = 0; j < 32; j++)
        v[j] = aload(rb + (j >> 3) * 512 + (j & 7) * 64);
#pragma unroll
      for (int i = 0; i < 4; i++)
        p[i] = aload(pb + i * 512);
      {
        int guard = 0;
        while (true) {
          u32 pend = 0;
#pragma unroll
          for (int j = 0; j < 32; j++) pend |= ((v[j] >> 16) ^ etag) & 1u;
#pragma unroll
          for (int i = 0; i < 4; i++) pend |= (u32)(p[i] == SENT);
          if (__builtin_expect(pend == 0u, 1)) break;
          if (++guard > (1 << 16)) break;
          __builtin_amdgcn_s_sleep(1);
#pragma unroll
          for (int j = 0; j < 32; j++)
            v[j] = aload(rb + (j >> 3) * 512 + (j & 7) * 64);
#pragma unroll
          for (int i = 0; i < 4; i++)
            p[i] = aload(pb + i * 512);
        }
      }
#pragma unroll
      for (int rr = 0; rr < 4; rr++) {
        const int row = w4 + rr;
        u32* wrow = &Ab[buf][row][0];
        const int xsw = (row & 7) << 2;
#pragma unroll
        for (int k = 0; k < 8; k++)
          wrow[(k * 64 + lane) ^ xsw] = v[rr * 8 + k];
      }
      __syncthreads();

      floatx4 ac[4];
#pragma unroll
      for (int q = 0; q < 4; q++) ac[q] = (floatx4){0.f, 0.f, 0.f, 0.f};
      const u32* arow = &Ab[buf][l16][0];
#pragma unroll
      for (int s = 0; s < 32; s += 4) {
#pragma unroll
        for (int q = 0; q < 4; q++) {
          bf16x8 a = __builtin_bit_cast(bf16x8,
              *(const u16x8*)(arow + (((s + q) * 16 + quad * 4) ^ xswr)));
          ac[q] = __builtin_amdgcn_mfma_f32_16x16x32_bf16(a, wfh[s + q], ac[q], 0, 0, 0);
        }
      }

      const u32 ntag = (u32)(((t + 1) >> 2) & 1);
#pragma unroll
      for (int i = 0; i < 4; i++) {
        const float vsum = ac[0][i] + ac[1][i] + ac[2][i] + ac[3][i] +
                           __builtin_bit_cast(float, p[i]);
        const float th = fast_tanh(vsum);
        const float nv = (t < lens[i]) ? th : hcur[i];
        hcur[i] = nv;
        const u16 hi = f2bf(nv);
        const u16 lo = f2bf(nv - bf2f(hi));
        u32 wv = (u32)hi | ((u32)lo << 16);
        wv = (wv & 0xFFFEFFFFu) | (ntag << 16);   // tag in lo-bf16 LSB
        astore(ring1 + (size_t)((t + 1) & 3) * 32768 +
                   (size_t)(g * 16 + quad * 4 + i) * 512 + mycol, wv);
      }
    }
#pragma unroll
    for (int i = 0; i < 4; i++) {
      const int b = g * 16 + quad * 4 + i;
      out[(size_t)b * 512 + mycol] = hcur[i];                    // h_last
      out[32768 + (size_t)b * 1024 + 512 + mycol] = hcur[i];     // hidden[:,1,:]
    }
  }
}

// ---------- sequential recurrence pass (one layer) — FALLBACK only ----------
__global__ __launch_bounds__(256, 1)
void rnn_pass(const u16* __restrict__ Whh, const float* __restrict__ Xpre,
              u32* __restrict__ hist, const int* __restrict__ lengths,
              float* __restrict__ out_last, float* __restrict__ out_hidden) {
  __shared__ u32 Abuf[2][16][512];
  const int tid = threadIdx.x;
  const int wave = tid >> 6, lane = tid & 63;
  const int quad = lane >> 4, l16 = lane & 15;
  const int c = blockIdx.x >> 2, g = blockIdx.x & 3;
  const int mycol = c * 64 + wave * 16 + l16;
  const int w4 = wave * 4;

  bf16x8 wfrag[32];
  {
    const u16* wrow = Whh + (size_t)mycol * 512 + quad * 4;
#pragma unroll
    for (int s = 0; s < 32; s++) {
      u16x4 w4v = *(const u16x4*)(wrow + s * 16);
      u16x8 w8 = {w4v[0], w4v[0], w4v[1], w4v[1], w4v[2], w4v[2], w4v[3], w4v[3]};
      wfrag[s] = __builtin_bit_cast(bf16x8, w8);
    }
  }
  float hcur[4];
  int lens[4];
#pragma unroll
  for (int i = 0; i < 4; i++) {
    hcur[i] = 0.f;
    lens[i] = lengths[g * 16 + quad * 4 + i];
  }
  const int xswr = (l16 & 7) << 2;

  for (int t = 0; t < TT; t++) {
    const int buf = t & 1;
    float pre[4];
#pragma unroll
    for (int i = 0; i < 4; i++)
      pre[i] = Xpre[(size_t)t * 32768 + (size_t)(g * 16 + quad * 4 + i) * 512 + mycol];

    u32 v[32];
    const u32* sbase = hist + (size_t)t * 32768 + (size_t)(g * 16 + w4) * 512 + lane;
#pragma unroll
    for (int j = 0; j < 32; j++)
      v[j] = aload(sbase + (j >> 3) * 512 + (j & 7) * 64);
    {
      int guard = 0;
      while (true) {
        u32 pend = 0;
#pragma unroll
        for (int j = 0; j < 32; j++) pend |= (u32)(v[j] == SENT);
        if (__builtin_expect(pend == 0u, 1)) break;
        if (++guard > (1 << 16)) break;
        __builtin_amdgcn_s_sleep(1);
#pragma unroll
        for (int j = 0; j < 32; j++)
          v[j] = aload(sbase + (j >> 3) * 512 + (j & 7) * 64);
      }
    }
#pragma unroll
    for (int rr = 0; rr < 4; rr++) {
      const int row = w4 + rr;
      u32* wrow = &Abuf[buf][row][0];
      const int xsw = (row & 7) << 2;
#pragma unroll
      for (int k = 0; k < 8; k++)
        wrow[(k * 64 + lane) ^ xsw] = v[rr * 8 + k];
    }
    __syncthreads();

    floatx4 ac[4];
#pragma unroll
    for (int q = 0; q < 4; q++) ac[q] = (floatx4){0.f, 0.f, 0.f, 0.f};
    const u32* arow = &Abuf[buf][l16][0];
#pragma unroll
    for (int s = 0; s < 32; s += 4) {
#pragma unroll
      for (int q = 0; q < 4; q++) {
        bf16x8 a = __builtin_bit_cast(bf16x8,
            *(const u16x8*)(arow + (((s + q) * 16 + quad * 4) ^ xswr)));
        ac[q] = __builtin_amdgcn_mfma_f32_16x16x32_bf16(a, wfrag[s + q], ac[q], 0, 0, 0);
      }
    }

#pragma unroll
    for (int i = 0; i < 4; i++) {
      const float vsum = ac[0][i] + ac[1][i] + ac[2][i] + ac[3][i] + pre[i];
      const float th = fast_tanh(vsum);
      const float nv = (t < lens[i]) ? th : hcur[i];
      hcur[i] = nv;
      const u16 hi = f2bf(nv);
      const u16 lo = f2bf(nv - bf2f(hi));
      u32 wv = (u32)hi | ((u32)lo << 16);
      wv += (wv == SENT);
      astore(hist + (size_t)(t + 1) * 32768 +
                 (size_t)(g * 16 + quad * 4 + i) * 512 + mycol, wv);
    }
  }
#pragma unroll
  for (int i = 0; i < 4; i++) {
    const int b = g * 16 + quad * 4 + i;
    if (out_hidden) out_hidden[(size_t)b * 1024 + mycol] = hcur[i];
    if (out_last)   out_last[(size_t)b * 512 + mycol] = hcur[i];
  }
}

// ---------- launch ----------
extern "C" void kernel_launch(void* const* d_in, const int* in_sizes, int n_in,
                              void* d_out, int out_size, void* d_ws, size_t ws_size,
                              hipStream_t stream) {
  const int*   x   = (const int*)d_in[0];
  const int*   len = (const int*)d_in[1];
  const float* emb = (const float*)d_in[2];
  const float* Wih = (const float*)d_in[3];
  const float* Whh = (const float*)d_in[4];
  const float* bih = (const float*)d_in[5];
  const float* bhh = (const float*)d_in[6];
  float* out = (float*)d_out;

  char* ws = (char*)d_ws;
  const size_t SZ_XPRE = 67108864;                 // T*B*512 fp32
  const size_t SZ_HIST = 67239936;                 // (T+1)*B*512 u32
  const size_t SZ_PRE1 = 67108864;                 // T*B*512 u32/fp32
  const size_t SZ_RING = 524288;                   // 4 slots * 131072
  const size_t SZ_WBF3 = 1572864;                  // 3 * 512*512 bf16

  const size_t need = SZ_XPRE + SZ_HIST + SZ_PRE1 + SZ_RING + SZ_WBF3 + 4096;
  if (ws_size >= need) {
    // ---------- merged 2-stage pipelined flow (R4 protocol) ----------
    float* Xpre  = (float*)(ws);
    u32*   hist0 = (u32*)(ws + SZ_XPRE);
    u32*   pre1  = (u32*)(ws + SZ_XPRE + SZ_HIST);
    u32*   ring1 = (u32*)(ws + SZ_XPRE + SZ_HIST + SZ_PRE1);
    u16*   wbf3  = (u16*)(ws + SZ_XPRE + SZ_HIST + SZ_PRE1 + SZ_RING);
    float* bsum  = (float*)(ws + SZ_XPRE + SZ_HIST + SZ_PRE1 + SZ_RING + SZ_WBF3);

    hipMemsetAsync(hist0, 0, 131072, stream);                               // h0(-1)=0
    hipMemsetAsync((char*)hist0 + 131072, 0xAA, (size_t)512 * 131072, stream); // poison
    hipMemsetAsync(pre1, 0xAA, SZ_PRE1, stream);                            // poison
    hipMemsetAsync(ring1, 0, 131072, stream);                               // h1(-1)=0, tag0
    hipMemsetAsync((char*)ring1 + 131072, 0xFF, 393216, stream);            // slots1-3: tag1
    hipLaunchKernelGGL(prep_kernel, dim3(512), dim3(256), 0, stream,
                       Wih, Whh, bih, bhh, wbf3, bsum);
    hipLaunchKernelGGL(gemm_pre, dim3(1024), dim3(256), 0, stream,
                       Wih /*fp32 wih0*/, bsum, emb, x, (const u32*)nullptr, Xpre, 0);
    hipLaunchKernelGGL(rnn_fused2, dim3(64), dim3(512), 0, stream,
                       wbf3, bsum, Xpre, hist0, pre1, ring1, len, out);
  } else {
    // ---------- fallback: proven sequential two-pass flow ----------
    float* Xpre  = (float*)(ws);
    u32*   hist  = (u32*)(ws + SZ_XPRE);
    u16*   wbf3  = (u16*)(ws + SZ_XPRE + SZ_HIST);
    float* bsum  = (float*)(ws + SZ_XPRE + SZ_HIST + SZ_WBF3);

    hipMemsetAsync(hist, 0, 131072, stream);
    hipMemsetAsync((char*)hist + 131072, 0xAA, (size_t)512 * 131072, stream);
    hipLaunchKernelGGL(prep_kernel, dim3(512), dim3(256), 0, stream,
                       Wih, Whh, bih, bhh, wbf3, bsum);
    hipLaunchKernelGGL(gemm_pre, dim3(1024), dim3(256), 0, stream,
                       Wih /*fp32 wih0*/, bsum, emb, x, (const u32*)nullptr, Xpre, 0);
    hipLaunchKernelGGL(rnn_pass, dim3(32), dim3(256), 0, stream,
                       wbf3 /*whh0*/, Xpre, hist, len,
                       (float*)nullptr, out + 32768);
    hipLaunchKernelGGL(gemm_pre, dim3(1024), dim3(256), 0, stream,
                       Wih + 262144 /*fp32 wih1*/, bsum + 512, (const float*)nullptr,
                       (const int*)nullptr, hist, Xpre, 1);
    hipMemsetAsync((char*)hist + 131072, 0xAA, (size_t)512 * 131072, stream);
    hipLaunchKernelGGL(rnn_pass, dim3(32), dim3(256), 0, stream,
                       wbf3 + 524288 /*whh1*/, Xpre, hist, len,
                       out, out + 32768 + 512);
  }
}

// Round 11
// 1627.420 us; speedup vs baseline: 1.8475x; 1.8475x over previous
//
#include <hip/hip_runtime.h>

typedef unsigned short u16;
typedef unsigned int   u32;
typedef __attribute__((ext_vector_type(4))) u16   u16x4;
typedef __attribute__((ext_vector_type(8))) u16   u16x8;
typedef __attribute__((ext_vector_type(8))) __bf16 bf16x8;
typedef __attribute__((ext_vector_type(4))) float  floatx4;
typedef __attribute__((ext_vector_type(4))) u32   u32x4;

#define TT 512   // seq len
#define BB 64    // batch
#define HD 512   // hidden/emb dim
#define SENT 0xAAAAAAAAu

// ---------- helpers ----------
__device__ __forceinline__ u16 f2bf(float f) {
  u32 u = __builtin_bit_cast(u32, f);
  u32 r = u + 0x7fffu + ((u >> 16) & 1u);   // round-to-nearest-even
  return (u16)(r >> 16);
}
__device__ __forceinline__ float bf2f(u16 h) {
  return __builtin_bit_cast(float, ((u32)h) << 16);
}
__device__ __forceinline__ float fast_tanh(float x) {
  float xc = fminf(fmaxf(x, -12.f), 12.f);
  float e = __expf(2.f * xc);
  return __fdividef(e - 1.f, e + 1.f);
}

// ---------- prep: convert 3 weight matrices to bf16, sum biases ----------
// wbf3 layout: [whh0 | wih1 | whh1], each 512*512
__global__ __launch_bounds__(256)
void prep_kernel(const float* __restrict__ W_ih, const float* __restrict__ W_hh,
                 const float* __restrict__ b_ih, const float* __restrict__ b_hh,
                 u16* __restrict__ wbf3, float* __restrict__ bsum) {
  int idx = blockIdx.x * blockDim.x + threadIdx.x;
  int stride = gridDim.x * blockDim.x;
  for (int i = idx; i < 3 * 262144; i += stride) {
    int mat = i >> 18;
    int off = i & 262143;
    const float* src = (mat == 0) ? W_hh : (mat == 1) ? (W_ih + 262144)
                                         : (W_hh + 262144);
    wbf3[i] = f2bf(src[off]);
  }
  if (idx < 1024) bsum[idx] = b_ih[idx] + b_hh[idx];
}

// ---------- pre-activation GEMM ----------
// Xpre[m][n] = A[m][:] @ W[n][:] + bsum[n],  M=T*B (m = t*64+b), K=512, N=512
// Weights BwF are FP32 (converted to bf16 on the fly).
// mode 0: A row = emb[x[b][t]] (fp32, cvt to bf16)
// mode 1: A row = hist[t+1][b][0:512] low 16 bits (hi bf16 of h0)  [fallback only]
__global__ __launch_bounds__(256, 2)
void gemm_pre(const float* __restrict__ BwF, const float* __restrict__ bsum,
              const float* __restrict__ embsrc, const int* __restrict__ xtok,
              const u32* __restrict__ hist, float* __restrict__ Xpre, int mode) {
  __shared__ u16 As[128][40];
  __shared__ u16 Bs[128][40];
  const int tid = threadIdx.x;
  const int wave = tid >> 6, lane = tid & 63;
  const int quad = lane >> 4, l16 = lane & 15;
  const int mtile = blockIdx.x >> 2, ntile = blockIdx.x & 3;
  const int m0 = mtile * 128, n0 = ntile * 128;
  const int srow = tid >> 1, half = tid & 1;

  const float* aF = nullptr; const u32* aU = nullptr;
  {
    const int grow = m0 + srow;
    if (mode == 0) {
      const int t = grow >> 6, b = grow & 63;
      const int tok = xtok[b * TT + t];
      aF = embsrc + (size_t)tok * 512 + half * 16;
    } else {
      aU = hist + (size_t)((grow >> 6) + 1) * 32768 + (size_t)(grow & 63) * 512 + half * 16;
    }
  }
  const float* bptrF = BwF + (size_t)(n0 + srow) * 512 + half * 16;

  floatx4 acc[2][8];
#pragma unroll
  for (int a = 0; a < 2; a++)
#pragma unroll
    for (int b = 0; b < 8; b++) acc[a][b] = (floatx4){0.f, 0.f, 0.f, 0.f};

  for (int ks = 0; ks < 16; ks++) {
    const int k0 = ks * 32;
    u32 packed[8];
    if (mode == 0) {
      const float4* p = (const float4*)(aF + k0);
      float4 f0 = p[0], f1 = p[1], f2 = p[2], f3 = p[3];
      float vals[16] = {f0.x, f0.y, f0.z, f0.w, f1.x, f1.y, f1.z, f1.w,
                        f2.x, f2.y, f2.z, f2.w, f3.x, f3.y, f3.z, f3.w};
#pragma unroll
      for (int j = 0; j < 8; j++)
        packed[j] = (u32)f2bf(vals[2 * j]) | ((u32)f2bf(vals[2 * j + 1]) << 16);
    } else {
      const u32x4* p = (const u32x4*)(aU + k0);
      u32x4 q0 = p[0], q1 = p[1], q2 = p[2], q3 = p[3];
      u32 w[16] = {q0[0], q0[1], q0[2], q0[3], q1[0], q1[1], q1[2], q1[3],
                   q2[0], q2[1], q2[2], q2[3], q3[0], q3[1], q3[2], q3[3]};
#pragma unroll
      for (int j = 0; j < 8; j++)
        packed[j] = (w[2 * j] & 0xffffu) | ((w[2 * j + 1] & 0xffffu) << 16);
    }
    {
      u32x4* adst = (u32x4*)&As[srow][half * 16];
      adst[0] = (u32x4){packed[0], packed[1], packed[2], packed[3]};
      adst[1] = (u32x4){packed[4], packed[5], packed[6], packed[7]};
    }
    {
      const float4* bp = (const float4*)(bptrF + k0);
      float4 f0 = bp[0], f1 = bp[1], f2 = bp[2], f3 = bp[3];
      float vals[16] = {f0.x, f0.y, f0.z, f0.w, f1.x, f1.y, f1.z, f1.w,
                        f2.x, f2.y, f2.z, f2.w, f3.x, f3.y, f3.z, f3.w};
      u32 bpk[8];
#pragma unroll
      for (int j = 0; j < 8; j++)
        bpk[j] = (u32)f2bf(vals[2 * j]) | ((u32)f2bf(vals[2 * j + 1]) << 16);
      u32x4* bdst = (u32x4*)&Bs[srow][half * 16];
      bdst[0] = (u32x4){bpk[0], bpk[1], bpk[2], bpk[3]};
      bdst[1] = (u32x4){bpk[4], bpk[5], bpk[6], bpk[7]};
    }
    __syncthreads();
    bf16x8 afr[2], bfr[8];
#pragma unroll
    for (int mt = 0; mt < 2; mt++)
      afr[mt] = __builtin_bit_cast(bf16x8, *(const u16x8*)&As[wave * 32 + mt * 16 + l16][quad * 8]);
#pragma unroll
    for (int nt = 0; nt < 8; nt++)
      bfr[nt] = __builtin_bit_cast(bf16x8, *(const u16x8*)&Bs[nt * 16 + l16][quad * 8]);
#pragma unroll
    for (int mt = 0; mt < 2; mt++)
#pragma unroll
      for (int nt = 0; nt < 8; nt++)
        acc[mt][nt] = __builtin_amdgcn_mfma_f32_16x16x32_bf16(afr[mt], bfr[nt], acc[mt][nt], 0, 0, 0);
    __syncthreads();
  }
  float bs[8];
#pragma unroll
  for (int nt = 0; nt < 8; nt++) bs[nt] = bsum[n0 + nt * 16 + l16];
#pragma unroll
  for (int mt = 0; mt < 2; mt++)
#pragma unroll
    for (int nt = 0; nt < 8; nt++)
#pragma unroll
      for (int i = 0; i < 4; i++) {
        const int gm = m0 + wave * 32 + mt * 16 + quad * 4 + i;
        Xpre[(size_t)gm * 512 + n0 + nt * 16 + l16] = acc[mt][nt][i] + bs[nt];
      }
}

// ---------- FUSED three-stage pipeline, one launch, 96 WGs ----------
// role 0 (bid  0..31): layer-0 recurrence  (proven 2.5us/step structure)
//   h0(t) = tanh(Xpre(t) + h0(t-1)@Whh0^T); publish to hist0 (SENT protocol)
// role 1 (bid 32..63): pre-activation producer
//   poll h0(t) from hist0[t+1]; pre1(t) = h0(t)@Wih1^T + bsum1;
//   publish fp32 words to pre1[] (SENT protocol, bump-if-collision)
// role 2 (bid 64..95): layer-1 recurrence
//   poll pre1(t) (4 words) + h1(t-1) from depth-4 RING with tag bit
//   (bit16 = lo-bf16 LSB = (s/4)&1 for state index s; bounded-lag<=1 makes
//   depth-4 reuse safe; no re-poisoning needed);
//   h1(t) = tanh(pre1(t) + h1(t-1)@Whh1^T); publish to ring.
// Every role: one 32-ish-word poll + one matmul -> each stage ~= proven rate.
__global__ __launch_bounds__(256, 1)
void rnn_fused3(const u16* __restrict__ wbf3, const float* __restrict__ bsum,
                const float* __restrict__ Xpre, u32* __restrict__ hist0,
                u32* __restrict__ pre1, u32* __restrict__ ring1,
                const int* __restrict__ lengths, float* __restrict__ out) {
  __shared__ u32 lds[16384];   // 64 KiB: [2][16][512] double-buffered staging
  u32 (*Ab)[16][512] = reinterpret_cast<u32 (*)[16][512]>(lds);
  const int tid = threadIdx.x;
  const int wave = tid >> 6, lane = tid & 63;
  const int quad = lane >> 4, l16 = lane & 15;
  const int bid = blockIdx.x;
  const int role = bid >> 5;
  const int sub = bid & 31;
  const int c = sub >> 2, g = sub & 3;
  const int mycol = c * 64 + wave * 16 + l16;
  const int w4 = wave * 4;
  const int xswr = (l16 & 7) << 2;

  if (role == 0) {
    // ================= layer 0 =================
    const u16* Whh = wbf3;   // whh0
    bf16x8 wfrag[32];
    {
      const u16* wrow = Whh + (size_t)mycol * 512 + quad * 4;
#pragma unroll
      for (int s = 0; s < 32; s++) {
        u16x4 w4v = *(const u16x4*)(wrow + s * 16);
        u16x8 w8 = {w4v[0], w4v[0], w4v[1], w4v[1], w4v[2], w4v[2], w4v[3], w4v[3]};
        wfrag[s] = __builtin_bit_cast(bf16x8, w8);
      }
    }
    float hcur[4];
    int lens[4];
#pragma unroll
    for (int i = 0; i < 4; i++) {
      hcur[i] = 0.f;
      lens[i] = lengths[g * 16 + quad * 4 + i];
    }
    for (int t = 0; t < TT; t++) {
      const int buf = t & 1;
      float pre[4];
#pragma unroll
      for (int i = 0; i < 4; i++)
        pre[i] = ((const float*)Xpre)[(size_t)t * 32768 + (size_t)(g * 16 + quad * 4 + i) * 512 + mycol];

      u32 v[32];
      const u32* sbase = hist0 + (size_t)t * 32768 + (size_t)(g * 16 + w4) * 512 + lane;
#pragma unroll
      for (int j = 0; j < 32; j++)
        v[j] = __hip_atomic_load(sbase + (j >> 3) * 512 + (j & 7) * 64,
                                 __ATOMIC_RELAXED, __HIP_MEMORY_SCOPE_AGENT);
      {
        int guard = 0;
        while (true) {
          u32 pend = 0;
#pragma unroll
          for (int j = 0; j < 32; j++) pend |= (u32)(v[j] == SENT);
          if (__builtin_expect(pend == 0u, 1)) break;
          if (++guard > (1 << 16)) break;
          __builtin_amdgcn_s_sleep(1);
#pragma unroll
          for (int j = 0; j < 32; j++)
            v[j] = __hip_atomic_load(sbase + (j >> 3) * 512 + (j & 7) * 64,
                                     __ATOMIC_RELAXED, __HIP_MEMORY_SCOPE_AGENT);
        }
      }
#pragma unroll
      for (int rr = 0; rr < 4; rr++) {
        const int row = w4 + rr;
        u32* wrow = &Ab[buf][row][0];
        const int xsw = (row & 7) << 2;
#pragma unroll
        for (int k = 0; k < 8; k++)
          wrow[(k * 64 + lane) ^ xsw] = v[rr * 8 + k];
      }
      __syncthreads();

      floatx4 ac[4];
#pragma unroll
      for (int q = 0; q < 4; q++) ac[q] = (floatx4){0.f, 0.f, 0.f, 0.f};
      const u32* arow = &Ab[buf][l16][0];
#pragma unroll
      for (int s = 0; s < 32; s += 4) {
#pragma unroll
        for (int q = 0; q < 4; q++) {
          bf16x8 a = __builtin_bit_cast(bf16x8,
              *(const u16x8*)(arow + (((s + q) * 16 + quad * 4) ^ xswr)));
          ac[q] = __builtin_amdgcn_mfma_f32_16x16x32_bf16(a, wfrag[s + q], ac[q], 0, 0, 0);
        }
      }

#pragma unroll
      for (int i = 0; i < 4; i++) {
        const float vsum = ac[0][i] + ac[1][i] + ac[2][i] + ac[3][i] + pre[i];
        const float th = fast_tanh(vsum);
        const float nv = (t < lens[i]) ? th : hcur[i];
        hcur[i] = nv;
        const u16 hi = f2bf(nv);
        const u16 lo = f2bf(nv - bf2f(hi));
        u32 wv = (u32)hi | ((u32)lo << 16);
        wv += (wv == SENT);
        __hip_atomic_store(hist0 + (size_t)(t + 1) * 32768 +
                               (size_t)(g * 16 + quad * 4 + i) * 512 + mycol,
                           wv, __ATOMIC_RELAXED, __HIP_MEMORY_SCOPE_AGENT);
      }
    }
#pragma unroll
    for (int i = 0; i < 4; i++) {
      const int b = g * 16 + quad * 4 + i;
      out[32768 + (size_t)b * 1024 + mycol] = hcur[i];   // hidden[:,0,:]
    }
  } else if (role == 1) {
    // ================= pre-activation producer =================
    const u16* Wih = wbf3 + 262144;   // wih1
    bf16x8 wfi[32];
    {
      const u16* wrow = Wih + (size_t)mycol * 512 + quad * 4;
#pragma unroll
      for (int s = 0; s < 32; s++) {
        u16x4 w4v = *(const u16x4*)(wrow + s * 16);
        u16x8 w8 = {w4v[0], w4v[0], w4v[1], w4v[1], w4v[2], w4v[2], w4v[3], w4v[3]};
        wfi[s] = __builtin_bit_cast(bf16x8, w8);
      }
    }
    const float bs1 = bsum[512 + mycol];
    for (int t = 0; t < TT; t++) {
      const int buf = t & 1;
      u32 v[32];
      const u32* sbase = hist0 + (size_t)(t + 1) * 32768 + (size_t)(g * 16 + w4) * 512 + lane;
#pragma unroll
      for (int j = 0; j < 32; j++)
        v[j] = __hip_atomic_load(sbase + (j >> 3) * 512 + (j & 7) * 64,
                                 __ATOMIC_RELAXED, __HIP_MEMORY_SCOPE_AGENT);
      {
        int guard = 0;
        while (true) {
          u32 pend = 0;
#pragma unroll
          for (int j = 0; j < 32; j++) pend |= (u32)(v[j] == SENT);
          if (__builtin_expect(pend == 0u, 1)) break;
          if (++guard > (1 << 16)) break;
          __builtin_amdgcn_s_sleep(1);
#pragma unroll
          for (int j = 0; j < 32; j++)
            v[j] = __hip_atomic_load(sbase + (j >> 3) * 512 + (j & 7) * 64,
                                     __ATOMIC_RELAXED, __HIP_MEMORY_SCOPE_AGENT);
        }
      }
#pragma unroll
      for (int rr = 0; rr < 4; rr++) {
        const int row = w4 + rr;
        u32* wrow = &Ab[buf][row][0];
        const int xsw = (row & 7) << 2;
#pragma unroll
        for (int k = 0; k < 8; k++)
          wrow[(k * 64 + lane) ^ xsw] = v[rr * 8 + k];
      }
      __syncthreads();

      floatx4 ac[4];
#pragma unroll
      for (int q = 0; q < 4; q++) ac[q] = (floatx4){0.f, 0.f, 0.f, 0.f};
      const u32* arow = &Ab[buf][l16][0];
#pragma unroll
      for (int s = 0; s < 32; s += 4) {
#pragma unroll
        for (int q = 0; q < 4; q++) {
          bf16x8 a = __builtin_bit_cast(bf16x8,
              *(const u16x8*)(arow + (((s + q) * 16 + quad * 4) ^ xswr)));
          ac[q] = __builtin_amdgcn_mfma_f32_16x16x32_bf16(a, wfi[s + q], ac[q], 0, 0, 0);
        }
      }

#pragma unroll
      for (int i = 0; i < 4; i++) {
        const float pv = ac[0][i] + ac[1][i] + ac[2][i] + ac[3][i] + bs1;
        u32 b = __builtin_bit_cast(u32, pv);
        b += (b == SENT);   // exclude sentinel (1 ulp)
        __hip_atomic_store(pre1 + (size_t)t * 32768 +
                               (size_t)(g * 16 + quad * 4 + i) * 512 + mycol,
                           b, __ATOMIC_RELAXED, __HIP_MEMORY_SCOPE_AGENT);
      }
    }
  } else {
    // ================= layer 1 =================
    const u16* Whh = wbf3 + 524288;   // whh1
    bf16x8 wfh[32];
    {
      const u16* wrow = Whh + (size_t)mycol * 512 + quad * 4;
#pragma unroll
      for (int s = 0; s < 32; s++) {
        u16x4 w4v = *(const u16x4*)(wrow + s * 16);
        u16x8 w8 = {w4v[0], w4v[0], w4v[1], w4v[1], w4v[2], w4v[2], w4v[3], w4v[3]};
        wfh[s] = __builtin_bit_cast(bf16x8, w8);
      }
    }
    float hcur[4];
    int lens[4];
#pragma unroll
    for (int i = 0; i < 4; i++) {
      hcur[i] = 0.f;
      lens[i] = lengths[g * 16 + quad * 4 + i];
    }
    for (int t = 0; t < TT; t++) {
      const int buf = t & 1;
      const u32 etag = (u32)((t >> 2) & 1);
      u32 v[32], p[4];
      const u32* rb = ring1 + (size_t)(t & 3) * 32768 + (size_t)(g * 16 + w4) * 512 + lane;
      const u32* pb = pre1 + (size_t)t * 32768 + (size_t)(g * 16 + quad * 4) * 512 + mycol;
#pragma unroll
      for (int j = 0; j < 32; j++)
        v[j] = __hip_atomic_load(rb + (j >> 3) * 512 + (j & 7) * 64,
                                 __ATOMIC_RELAXED, __HIP_MEMORY_SCOPE_AGENT);
#pragma unroll
      for (int i = 0; i < 4; i++)
        p[i] = __hip_atomic_load(pb + i * 512,
                                 __ATOMIC_RELAXED, __HIP_MEMORY_SCOPE_AGENT);
      {
        int guard = 0;
        while (true) {
          u32 pend = 0;
#pragma unroll
          for (int j = 0; j < 32; j++) pend |= ((v[j] >> 16) ^ etag) & 1u;
#pragma unroll
          for (int i = 0; i < 4; i++) pend |= (u32)(p[i] == SENT);
          if (__builtin_expect(pend == 0u, 1)) break;
          if (++guard > (1 << 16)) break;
          __builtin_amdgcn_s_sleep(1);
#pragma unroll
          for (int j = 0; j < 32; j++)
            v[j] = __hip_atomic_load(rb + (j >> 3) * 512 + (j & 7) * 64,
                                     __ATOMIC_RELAXED, __HIP_MEMORY_SCOPE_AGENT);
#pragma unroll
          for (int i = 0; i < 4; i++)
            p[i] = __hip_atomic_load(pb + i * 512,
                                     __ATOMIC_RELAXED, __HIP_MEMORY_SCOPE_AGENT);
        }
      }
#pragma unroll
      for (int rr = 0; rr < 4; rr++) {
        const int row = w4 + rr;
        u32* wrow = &Ab[buf][row][0];
        const int xsw = (row & 7) << 2;
#pragma unroll
        for (int k = 0; k < 8; k++)
          wrow[(k * 64 + lane) ^ xsw] = v[rr * 8 + k];
      }
      __syncthreads();

      floatx4 ac[4];
#pragma unroll
      for (int q = 0; q < 4; q++) ac[q] = (floatx4){0.f, 0.f, 0.f, 0.f};
      const u32* arow = &Ab[buf][l16][0];
#pragma unroll
      for (int s = 0; s < 32; s += 4) {
#pragma unroll
        for (int q = 0; q < 4; q++) {
          bf16x8 a = __builtin_bit_cast(bf16x8,
              *(const u16x8*)(arow + (((s + q) * 16 + quad * 4) ^ xswr)));
          ac[q] = __builtin_amdgcn_mfma_f32_16x16x32_bf16(a, wfh[s + q], ac[q], 0, 0, 0);
        }
      }

      const u32 ntag = (u32)(((t + 1) >> 2) & 1);
#pragma unroll
      for (int i = 0; i < 4; i++) {
        const float vsum = ac[0][i] + ac[1][i] + ac[2][i] + ac[3][i] +
                           __builtin_bit_cast(float, p[i]);
        const float th = fast_tanh(vsum);
        const float nv = (t < lens[i]) ? th : hcur[i];
        hcur[i] = nv;
        const u16 hi = f2bf(nv);
        const u16 lo = f2bf(nv - bf2f(hi));
        u32 wv = (u32)hi | ((u32)lo << 16);
        wv = (wv & 0xFFFEFFFFu) | (ntag << 16);   // tag in lo-bf16 LSB
        __hip_atomic_store(ring1 + (size_t)((t + 1) & 3) * 32768 +
                               (size_t)(g * 16 + quad * 4 + i) * 512 + mycol,
                           wv, __ATOMIC_RELAXED, __HIP_MEMORY_SCOPE_AGENT);
      }
    }
#pragma unroll
    for (int i = 0; i < 4; i++) {
      const int b = g * 16 + quad * 4 + i;
      out[(size_t)b * 512 + mycol] = hcur[i];                    // h_last
      out[32768 + (size_t)b * 1024 + 512 + mycol] = hcur[i];     // hidden[:,1,:]
    }
  }
}

// ---------- sequential recurrence pass (one layer) — FALLBACK only ----------
__global__ __launch_bounds__(256, 1)
void rnn_pass(const u16* __restrict__ Whh, const float* __restrict__ Xpre,
              u32* __restrict__ hist, const int* __restrict__ lengths,
              float* __restrict__ out_last, float* __restrict__ out_hidden) {
  __shared__ u32 Abuf[2][16][512];
  const int tid = threadIdx.x;
  const int wave = tid >> 6, lane = tid & 63;
  const int quad = lane >> 4, l16 = lane & 15;
  const int c = blockIdx.x >> 2, g = blockIdx.x & 3;
  const int mycol = c * 64 + wave * 16 + l16;
  const int w4 = wave * 4;

  bf16x8 wfrag[32];
  {
    const u16* wrow = Whh + (size_t)mycol * 512 + quad * 4;
#pragma unroll
    for (int s = 0; s < 32; s++) {
      u16x4 w4v = *(const u16x4*)(wrow + s * 16);
      u16x8 w8 = {w4v[0], w4v[0], w4v[1], w4v[1], w4v[2], w4v[2], w4v[3], w4v[3]};
      wfrag[s] = __builtin_bit_cast(bf16x8, w8);
    }
  }
  float hcur[4];
  int lens[4];
#pragma unroll
  for (int i = 0; i < 4; i++) {
    hcur[i] = 0.f;
    lens[i] = lengths[g * 16 + quad * 4 + i];
  }
  const int xswr = (l16 & 7) << 2;

  for (int t = 0; t < TT; t++) {
    const int buf = t & 1;
    float pre[4];
#pragma unroll
    for (int i = 0; i < 4; i++)
      pre[i] = Xpre[(size_t)t * 32768 + (size_t)(g * 16 + quad * 4 + i) * 512 + mycol];

    u32 v[32];
    const u32* sbase = hist + (size_t)t * 32768 + (size_t)(g * 16 + w4) * 512 + lane;
#pragma unroll
    for (int j = 0; j < 32; j++)
      v[j] = __hip_atomic_load(sbase + (j >> 3) * 512 + (j & 7) * 64,
                               __ATOMIC_RELAXED, __HIP_MEMORY_SCOPE_AGENT);
    {
      int guard = 0;
      while (true) {
        u32 pend = 0;
#pragma unroll
        for (int j = 0; j < 32; j++) pend |= (u32)(v[j] == SENT);
        if (__builtin_expect(pend == 0u, 1)) break;
        if (++guard > (1 << 16)) break;
        __builtin_amdgcn_s_sleep(1);
#pragma unroll
        for (int j = 0; j < 32; j++)
          v[j] = __hip_atomic_load(sbase + (j >> 3) * 512 + (j & 7) * 64,
                                   __ATOMIC_RELAXED, __HIP_MEMORY_SCOPE_AGENT);
      }
    }
#pragma unroll
    for (int rr = 0; rr < 4; rr++) {
      const int row = w4 + rr;
      u32* wrow = &Abuf[buf][row][0];
      const int xsw = (row & 7) << 2;
#pragma unroll
      for (int k = 0; k < 8; k++)
        wrow[(k * 64 + lane) ^ xsw] = v[rr * 8 + k];
    }
    __syncthreads();

    floatx4 ac[4];
#pragma unroll
    for (int q = 0; q < 4; q++) ac[q] = (floatx4){0.f, 0.f, 0.f, 0.f};
    const u32* arow = &Abuf[buf][l16][0];
#pragma unroll
    for (int s = 0; s < 32; s += 4) {
#pragma unroll
      for (int q = 0; q < 4; q++) {
        bf16x8 a = __builtin_bit_cast(bf16x8,
            *(const u16x8*)(arow + (((s + q) * 16 + quad * 4) ^ xswr)));
        ac[q] = __builtin_amdgcn_mfma_f32_16x16x32_bf16(a, wfrag[s + q], ac[q], 0, 0, 0);
      }
    }

#pragma unroll
    for (int i = 0; i < 4; i++) {
      const float vsum = ac[0][i] + ac[1][i] + ac[2][i] + ac[3][i] + pre[i];
      const float th = fast_tanh(vsum);
      const float nv = (t < lens[i]) ? th : hcur[i];
      hcur[i] = nv;
      const u16 hi = f2bf(nv);
      const u16 lo = f2bf(nv - bf2f(hi));
      u32 wv = (u32)hi | ((u32)lo << 16);
      wv += (wv == SENT);
      __hip_atomic_store(hist + (size_t)(t + 1) * 32768 +
                             (size_t)(g * 16 + quad * 4 + i) * 512 + mycol,
                         wv, __ATOMIC_RELAXED, __HIP_MEMORY_SCOPE_AGENT);
    }
  }
#pragma unroll
  for (int i = 0; i < 4; i++) {
    const int b = g * 16 + quad * 4 + i;
    if (out_hidden) out_hidden[(size_t)b * 1024 + mycol] = hcur[i];
    if (out_last)   out_last[(size_t)b * 512 + mycol] = hcur[i];
  }
}

// ---------- launch ----------
extern "C" void kernel_launch(void* const* d_in, const int* in_sizes, int n_in,
                              void* d_out, int out_size, void* d_ws, size_t ws_size,
                              hipStream_t stream) {
  const int*   x   = (const int*)d_in[0];
  const int*   len = (const int*)d_in[1];
  const float* emb = (const float*)d_in[2];
  const float* Wih = (const float*)d_in[3];
  const float* Whh = (const float*)d_in[4];
  const float* bih = (const float*)d_in[5];
  const float* bhh = (const float*)d_in[6];
  float* out = (float*)d_out;

  char* ws = (char*)d_ws;
  const size_t SZ_XPRE = 67108864;                 // T*B*512 fp32
  const size_t SZ_HIST = 67239936;                 // (T+1)*B*512 u32
  const size_t SZ_PRE1 = 67108864;                 // T*B*512 u32/fp32
  const size_t SZ_RING = 524288;                   // 4 slots * 131072
  const size_t SZ_WBF3 = 1572864;                  // 3 * 512*512 bf16

  const size_t need3 = SZ_XPRE + SZ_HIST + SZ_PRE1 + SZ_RING + SZ_WBF3 + 4096;
  if (ws_size >= need3) {
    // ---------- 3-stage pipelined flow ----------
    float* Xpre  = (float*)(ws);
    u32*   hist0 = (u32*)(ws + SZ_XPRE);
    u32*   pre1  = (u32*)(ws + SZ_XPRE + SZ_HIST);
    u32*   ring1 = (u32*)(ws + SZ_XPRE + SZ_HIST + SZ_PRE1);
    u16*   wbf3  = (u16*)(ws + SZ_XPRE + SZ_HIST + SZ_PRE1 + SZ_RING);
    float* bsum  = (float*)(ws + SZ_XPRE + SZ_HIST + SZ_PRE1 + SZ_RING + SZ_WBF3);

    hipMemsetAsync(hist0, 0, 131072, stream);                               // h0(-1)=0
    hipMemsetAsync((char*)hist0 + 131072, 0xAA, (size_t)512 * 131072, stream); // poison
    hipMemsetAsync(pre1, 0xAA, SZ_PRE1, stream);                            // poison
    hipMemsetAsync(ring1, 0, 131072, stream);                               // h1(-1)=0, tag0
    hipMemsetAsync((char*)ring1 + 131072, 0xFF, 393216, stream);            // slots1-3: tag1
    hipLaunchKernelGGL(prep_kernel, dim3(512), dim3(256), 0, stream, Wih, Whh, bih, bhh, wbf3, bsum);
    hipLaunchKernelGGL(gemm_pre, dim3(1024), dim3(256), 0, stream,
                       Wih /*fp32 wih0*/, bsum, emb, x, (const u32*)nullptr, Xpre, 0);
    hipLaunchKernelGGL(rnn_fused3, dim3(96), dim3(256), 0, stream,
                       wbf3, bsum, Xpre, hist0, pre1, ring1, len, out);
  } else {
    // ---------- fallback: proven sequential two-pass flow ----------
    float* Xpre  = (float*)(ws);
    u32*   hist  = (u32*)(ws + SZ_XPRE);
    u16*   wbf3  = (u16*)(ws + SZ_XPRE + SZ_HIST);
    float* bsum  = (float*)(ws + SZ_XPRE + SZ_HIST + SZ_WBF3);

    hipMemsetAsync(hist, 0, 131072, stream);
    hipMemsetAsync((char*)hist + 131072, 0xAA, (size_t)512 * 131072, stream);
    hipLaunchKernelGGL(prep_kernel, dim3(512), dim3(256), 0, stream, Wih, Whh, bih, bhh, wbf3, bsum);
    hipLaunchKernelGGL(gemm_pre, dim3(1024), dim3(256), 0, stream,
                       Wih /*fp32 wih0*/, bsum, emb, x, (const u32*)nullptr, Xpre, 0);
    hipLaunchKernelGGL(rnn_pass, dim3(32), dim3(256), 0, stream,
                       wbf3 /*whh0*/, Xpre, hist, len,
                       (float*)nullptr, out + 32768);
    hipLaunchKernelGGL(gemm_pre, dim3(1024), dim3(256), 0, stream,
                       Wih + 262144 /*fp32 wih1*/, bsum + 512, (const float*)nullptr, (const int*)nullptr,
                       hist, Xpre, 1);
    hipMemsetAsync((char*)hist + 131072, 0xAA, (size_t)512 * 131072, stream);
    hipLaunchKernelGGL(rnn_pass, dim3(32), dim3(256), 0, stream,
                       wbf3 + 524288 /*whh1*/, Xpre, hist, len,
                       out, out + 32768 + 512);
  }
}

// Round 12
// 1616.464 us; speedup vs baseline: 1.8600x; 1.0068x over previous
//
#include <hip/hip_runtime.h>

typedef unsigned short u16;
typedef unsigned int   u32;
typedef __attribute__((ext_vector_type(4))) u16   u16x4;
typedef __attribute__((ext_vector_type(8))) u16   u16x8;
typedef __attribute__((ext_vector_type(8))) __bf16 bf16x8;
typedef __attribute__((ext_vector_type(4))) float  floatx4;
typedef __attribute__((ext_vector_type(4))) u32   u32x4;

#define TT 512   // seq len
#define BB 64    // batch
#define HD 512   // hidden/emb dim
#define SENT 0xAAAAAAAAu

// ---------- helpers ----------
__device__ __forceinline__ u16 f2bf(float f) {
  u32 u = __builtin_bit_cast(u32, f);
  u32 r = u + 0x7fffu + ((u >> 16) & 1u);   // round-to-nearest-even
  return (u16)(r >> 16);
}
__device__ __forceinline__ float bf2f(u16 h) {
  return __builtin_bit_cast(float, ((u32)h) << 16);
}
__device__ __forceinline__ float fast_tanh(float x) {
  float xc = fminf(fmaxf(x, -12.f), 12.f);
  float e = __expf(2.f * xc);
  return __fdividef(e - 1.f, e + 1.f);
}

// ---------- prep: convert 3 weight matrices to bf16, sum biases ----------
// wbf3 layout: [whh0 | wih1 | whh1], each 512*512
__global__ __launch_bounds__(256)
void prep_kernel(const float* __restrict__ W_ih, const float* __restrict__ W_hh,
                 const float* __restrict__ b_ih, const float* __restrict__ b_hh,
                 u16* __restrict__ wbf3, float* __restrict__ bsum) {
  int idx = blockIdx.x * blockDim.x + threadIdx.x;
  int stride = gridDim.x * blockDim.x;
  for (int i = idx; i < 3 * 262144; i += stride) {
    int mat = i >> 18;
    int off = i & 262143;
    const float* src = (mat == 0) ? W_hh : (mat == 1) ? (W_ih + 262144)
                                         : (W_hh + 262144);
    wbf3[i] = f2bf(src[off]);
  }
  if (idx < 1024) bsum[idx] = b_ih[idx] + b_hh[idx];
}

// ---------- pre-activation GEMM ----------
// Xpre[m][n] = A[m][:] @ W[n][:] + bsum[n],  M=T*B (m = t*64+b), K=512, N=512
// Weights BwF are FP32 (converted to bf16 on the fly).
// mode 0: A row = emb[x[b][t]] (fp32, cvt to bf16)
// mode 1: A row = hist[t+1][b][0:512] low 16 bits (hi bf16 of h0)  [fallback only]
__global__ __launch_bounds__(256, 2)
void gemm_pre(const float* __restrict__ BwF, const float* __restrict__ bsum,
              const float* __restrict__ embsrc, const int* __restrict__ xtok,
              const u32* __restrict__ hist, float* __restrict__ Xpre, int mode) {
  __shared__ u16 As[128][40];
  __shared__ u16 Bs[128][40];
  const int tid = threadIdx.x;
  const int wave = tid >> 6, lane = tid & 63;
  const int quad = lane >> 4, l16 = lane & 15;
  const int mtile = blockIdx.x >> 2, ntile = blockIdx.x & 3;
  const int m0 = mtile * 128, n0 = ntile * 128;
  const int srow = tid >> 1, half = tid & 1;

  const float* aF = nullptr; const u32* aU = nullptr;
  {
    const int grow = m0 + srow;
    if (mode == 0) {
      const int t = grow >> 6, b = grow & 63;
      const int tok = xtok[b * TT + t];
      aF = embsrc + (size_t)tok * 512 + half * 16;
    } else {
      aU = hist + (size_t)((grow >> 6) + 1) * 32768 + (size_t)(grow & 63) * 512 + half * 16;
    }
  }
  const float* bptrF = BwF + (size_t)(n0 + srow) * 512 + half * 16;

  floatx4 acc[2][8];
#pragma unroll
  for (int a = 0; a < 2; a++)
#pragma unroll
    for (int b = 0; b < 8; b++) acc[a][b] = (floatx4){0.f, 0.f, 0.f, 0.f};

  for (int ks = 0; ks < 16; ks++) {
    const int k0 = ks * 32;
    u32 packed[8];
    if (mode == 0) {
      const float4* p = (const float4*)(aF + k0);
      float4 f0 = p[0], f1 = p[1], f2 = p[2], f3 = p[3];
      float vals[16] = {f0.x, f0.y, f0.z, f0.w, f1.x, f1.y, f1.z, f1.w,
                        f2.x, f2.y, f2.z, f2.w, f3.x, f3.y, f3.z, f3.w};
#pragma unroll
      for (int j = 0; j < 8; j++)
        packed[j] = (u32)f2bf(vals[2 * j]) | ((u32)f2bf(vals[2 * j + 1]) << 16);
    } else {
      const u32x4* p = (const u32x4*)(aU + k0);
      u32x4 q0 = p[0], q1 = p[1], q2 = p[2], q3 = p[3];
      u32 w[16] = {q0[0], q0[1], q0[2], q0[3], q1[0], q1[1], q1[2], q1[3],
                   q2[0], q2[1], q2[2], q2[3], q3[0], q3[1], q3[2], q3[3]};
#pragma unroll
      for (int j = 0; j < 8; j++)
        packed[j] = (w[2 * j] & 0xffffu) | ((w[2 * j + 1] & 0xffffu) << 16);
    }
    {
      u32x4* adst = (u32x4*)&As[srow][half * 16];
      adst[0] = (u32x4){packed[0], packed[1], packed[2], packed[3]};
      adst[1] = (u32x4){packed[4], packed[5], packed[6], packed[7]};
    }
    {
      const float4* bp = (const float4*)(bptrF + k0);
      float4 f0 = bp[0], f1 = bp[1], f2 = bp[2], f3 = bp[3];
      float vals[16] = {f0.x, f0.y, f0.z, f0.w, f1.x, f1.y, f1.z, f1.w,
                        f2.x, f2.y, f2.z, f2.w, f3.x, f3.y, f3.z, f3.w};
      u32 bpk[8];
#pragma unroll
      for (int j = 0; j < 8; j++)
        bpk[j] = (u32)f2bf(vals[2 * j]) | ((u32)f2bf(vals[2 * j + 1]) << 16);
      u32x4* bdst = (u32x4*)&Bs[srow][half * 16];
      bdst[0] = (u32x4){bpk[0], bpk[1], bpk[2], bpk[3]};
      bdst[1] = (u32x4){bpk[4], bpk[5], bpk[6], bpk[7]};
    }
    __syncthreads();
    bf16x8 afr[2], bfr[8];
#pragma unroll
    for (int mt = 0; mt < 2; mt++)
      afr[mt] = __builtin_bit_cast(bf16x8, *(const u16x8*)&As[wave * 32 + mt * 16 + l16][quad * 8]);
#pragma unroll
    for (int nt = 0; nt < 8; nt++)
      bfr[nt] = __builtin_bit_cast(bf16x8, *(const u16x8*)&Bs[nt * 16 + l16][quad * 8]);
#pragma unroll
    for (int mt = 0; mt < 2; mt++)
#pragma unroll
      for (int nt = 0; nt < 8; nt++)
        acc[mt][nt] = __builtin_amdgcn_mfma_f32_16x16x32_bf16(afr[mt], bfr[nt], acc[mt][nt], 0, 0, 0);
    __syncthreads();
  }
  float bs[8];
#pragma unroll
  for (int nt = 0; nt < 8; nt++) bs[nt] = bsum[n0 + nt * 16 + l16];
#pragma unroll
  for (int mt = 0; mt < 2; mt++)
#pragma unroll
    for (int nt = 0; nt < 8; nt++)
#pragma unroll
      for (int i = 0; i < 4; i++) {
        const int gm = m0 + wave * 32 + mt * 16 + quad * 4 + i;
        Xpre[(size_t)gm * 512 + n0 + nt * 16 + l16] = acc[mt][nt][i] + bs[nt];
      }
}

// ---------- FUSED three-stage pipeline, one launch, 96 WGs ----------
// role 0 (bid  0..31): layer-0 recurrence  (critical edge, aggressive poll)
//   h0(t) = tanh(Xpre(t) + h0(t-1)@Whh0^T); publish to hist0 (SENT protocol)
// role 1 (bid 32..63): pre-activation producer (FOLLOWER edge, LAZY poll —
//   s_sleep(16): its detection latency only phase-shifts the pipeline, while
//   its aggressive sweeps were contending on the SAME hist0[t+1] words that
//   role-0's critical next-step poll waits on)
// role 2 (bid 64..95): layer-1 recurrence (ring edge critical: aggressive)
//   poll pre1(t) (4 words) + h1(t-1) from depth-4 RING with tag bit;
//   h1(t) = tanh(pre1(t) + h1(t-1)@Whh1^T); publish to ring.
__global__ __launch_bounds__(256, 1)
void rnn_fused3(const u16* __restrict__ wbf3, const float* __restrict__ bsum,
                const float* __restrict__ Xpre, u32* __restrict__ hist0,
                u32* __restrict__ pre1, u32* __restrict__ ring1,
                const int* __restrict__ lengths, float* __restrict__ out) {
  __shared__ u32 lds[16384];   // 64 KiB: [2][16][512] double-buffered staging
  u32 (*Ab)[16][512] = reinterpret_cast<u32 (*)[16][512]>(lds);
  const int tid = threadIdx.x;
  const int wave = tid >> 6, lane = tid & 63;
  const int quad = lane >> 4, l16 = lane & 15;
  const int bid = blockIdx.x;
  const int role = bid >> 5;
  const int sub = bid & 31;
  const int c = sub >> 2, g = sub & 3;
  const int mycol = c * 64 + wave * 16 + l16;
  const int w4 = wave * 4;
  const int xswr = (l16 & 7) << 2;

  if (role == 0) {
    // ================= layer 0 =================
    const u16* Whh = wbf3;   // whh0
    bf16x8 wfrag[32];
    {
      const u16* wrow = Whh + (size_t)mycol * 512 + quad * 4;
#pragma unroll
      for (int s = 0; s < 32; s++) {
        u16x4 w4v = *(const u16x4*)(wrow + s * 16);
        u16x8 w8 = {w4v[0], w4v[0], w4v[1], w4v[1], w4v[2], w4v[2], w4v[3], w4v[3]};
        wfrag[s] = __builtin_bit_cast(bf16x8, w8);
      }
    }
    float hcur[4];
    int lens[4];
#pragma unroll
    for (int i = 0; i < 4; i++) {
      hcur[i] = 0.f;
      lens[i] = lengths[g * 16 + quad * 4 + i];
    }
    for (int t = 0; t < TT; t++) {
      const int buf = t & 1;
      float pre[4];
#pragma unroll
      for (int i = 0; i < 4; i++)
        pre[i] = ((const float*)Xpre)[(size_t)t * 32768 + (size_t)(g * 16 + quad * 4 + i) * 512 + mycol];

      u32 v[32];
      const u32* sbase = hist0 + (size_t)t * 32768 + (size_t)(g * 16 + w4) * 512 + lane;
#pragma unroll
      for (int j = 0; j < 32; j++)
        v[j] = __hip_atomic_load(sbase + (j >> 3) * 512 + (j & 7) * 64,
                                 __ATOMIC_RELAXED, __HIP_MEMORY_SCOPE_AGENT);
      {
        int guard = 0;
        while (true) {
          u32 pend = 0;
#pragma unroll
          for (int j = 0; j < 32; j++) pend |= (u32)(v[j] == SENT);
          if (__builtin_expect(pend == 0u, 1)) break;
          if (++guard > (1 << 16)) break;
          __builtin_amdgcn_s_sleep(1);
#pragma unroll
          for (int j = 0; j < 32; j++)
            v[j] = __hip_atomic_load(sbase + (j >> 3) * 512 + (j & 7) * 64,
                                     __ATOMIC_RELAXED, __HIP_MEMORY_SCOPE_AGENT);
        }
      }
#pragma unroll
      for (int rr = 0; rr < 4; rr++) {
        const int row = w4 + rr;
        u32* wrow = &Ab[buf][row][0];
        const int xsw = (row & 7) << 2;
#pragma unroll
        for (int k = 0; k < 8; k++)
          wrow[(k * 64 + lane) ^ xsw] = v[rr * 8 + k];
      }
      __syncthreads();

      floatx4 ac[4];
#pragma unroll
      for (int q = 0; q < 4; q++) ac[q] = (floatx4){0.f, 0.f, 0.f, 0.f};
      const u32* arow = &Ab[buf][l16][0];
#pragma unroll
      for (int s = 0; s < 32; s += 4) {
#pragma unroll
        for (int q = 0; q < 4; q++) {
          bf16x8 a = __builtin_bit_cast(bf16x8,
              *(const u16x8*)(arow + (((s + q) * 16 + quad * 4) ^ xswr)));
          ac[q] = __builtin_amdgcn_mfma_f32_16x16x32_bf16(a, wfrag[s + q], ac[q], 0, 0, 0);
        }
      }

#pragma unroll
      for (int i = 0; i < 4; i++) {
        const float vsum = ac[0][i] + ac[1][i] + ac[2][i] + ac[3][i] + pre[i];
        const float th = fast_tanh(vsum);
        const float nv = (t < lens[i]) ? th : hcur[i];
        hcur[i] = nv;
        const u16 hi = f2bf(nv);
        const u16 lo = f2bf(nv - bf2f(hi));
        u32 wv = (u32)hi | ((u32)lo << 16);
        wv += (wv == SENT);
        __hip_atomic_store(hist0 + (size_t)(t + 1) * 32768 +
                               (size_t)(g * 16 + quad * 4 + i) * 512 + mycol,
                           wv, __ATOMIC_RELAXED, __HIP_MEMORY_SCOPE_AGENT);
      }
    }
#pragma unroll
    for (int i = 0; i < 4; i++) {
      const int b = g * 16 + quad * 4 + i;
      out[32768 + (size_t)b * 1024 + mycol] = hcur[i];   // hidden[:,0,:]
    }
  } else if (role == 1) {
    // ================= pre-activation producer (lazy follower poll) ========
    const u16* Wih = wbf3 + 262144;   // wih1
    bf16x8 wfi[32];
    {
      const u16* wrow = Wih + (size_t)mycol * 512 + quad * 4;
#pragma unroll
      for (int s = 0; s < 32; s++) {
        u16x4 w4v = *(const u16x4*)(wrow + s * 16);
        u16x8 w8 = {w4v[0], w4v[0], w4v[1], w4v[1], w4v[2], w4v[2], w4v[3], w4v[3]};
        wfi[s] = __builtin_bit_cast(bf16x8, w8);
      }
    }
    const float bs1 = bsum[512 + mycol];
    for (int t = 0; t < TT; t++) {
      const int buf = t & 1;
      u32 v[32];
      const u32* sbase = hist0 + (size_t)(t + 1) * 32768 + (size_t)(g * 16 + w4) * 512 + lane;
#pragma unroll
      for (int j = 0; j < 32; j++)
        v[j] = __hip_atomic_load(sbase + (j >> 3) * 512 + (j & 7) * 64,
                                 __ATOMIC_RELAXED, __HIP_MEMORY_SCOPE_AGENT);
      {
        int guard = 0;
        while (true) {
          u32 pend = 0;
#pragma unroll
          for (int j = 0; j < 32; j++) pend |= (u32)(v[j] == SENT);
          if (__builtin_expect(pend == 0u, 1)) break;
          if (++guard > (1 << 16)) break;
          __builtin_amdgcn_s_sleep(16);   // LAZY: follower edge, detection
                                          // latency only phase-shifts; cuts
                                          // contention on role-0's hot words
#pragma unroll
          for (int j = 0; j < 32; j++)
            v[j] = __hip_atomic_load(sbase + (j >> 3) * 512 + (j & 7) * 64,
                                     __ATOMIC_RELAXED, __HIP_MEMORY_SCOPE_AGENT);
        }
      }
#pragma unroll
      for (int rr = 0; rr < 4; rr++) {
        const int row = w4 + rr;
        u32* wrow = &Ab[buf][row][0];
        const int xsw = (row & 7) << 2;
#pragma unroll
        for (int k = 0; k < 8; k++)
          wrow[(k * 64 + lane) ^ xsw] = v[rr * 8 + k];
      }
      __syncthreads();

      floatx4 ac[4];
#pragma unroll
      for (int q = 0; q < 4; q++) ac[q] = (floatx4){0.f, 0.f, 0.f, 0.f};
      const u32* arow = &Ab[buf][l16][0];
#pragma unroll
      for (int s = 0; s < 32; s += 4) {
#pragma unroll
        for (int q = 0; q < 4; q++) {
          bf16x8 a = __builtin_bit_cast(bf16x8,
              *(const u16x8*)(arow + (((s + q) * 16 + quad * 4) ^ xswr)));
          ac[q] = __builtin_amdgcn_mfma_f32_16x16x32_bf16(a, wfi[s + q], ac[q], 0, 0, 0);
        }
      }

#pragma unroll
      for (int i = 0; i < 4; i++) {
        const float pv = ac[0][i] + ac[1][i] + ac[2][i] + ac[3][i] + bs1;
        u32 b = __builtin_bit_cast(u32, pv);
        b += (b == SENT);   // exclude sentinel (1 ulp)
        __hip_atomic_store(pre1 + (size_t)t * 32768 +
                               (size_t)(g * 16 + quad * 4 + i) * 512 + mycol,
                           b, __ATOMIC_RELAXED, __HIP_MEMORY_SCOPE_AGENT);
      }
    }
  } else {
    // ================= layer 1 =================
    const u16* Whh = wbf3 + 524288;   // whh1
    bf16x8 wfh[32];
    {
      const u16* wrow = Whh + (size_t)mycol * 512 + quad * 4;
#pragma unroll
      for (int s = 0; s < 32; s++) {
        u16x4 w4v = *(const u16x4*)(wrow + s * 16);
        u16x8 w8 = {w4v[0], w4v[0], w4v[1], w4v[1], w4v[2], w4v[2], w4v[3], w4v[3]};
        wfh[s] = __builtin_bit_cast(bf16x8, w8);
      }
    }
    float hcur[4];
    int lens[4];
#pragma unroll
    for (int i = 0; i < 4; i++) {
      hcur[i] = 0.f;
      lens[i] = lengths[g * 16 + quad * 4 + i];
    }
    for (int t = 0; t < TT; t++) {
      const int buf = t & 1;
      const u32 etag = (u32)((t >> 2) & 1);
      u32 v[32], p[4];
      const u32* rb = ring1 + (size_t)(t & 3) * 32768 + (size_t)(g * 16 + w4) * 512 + lane;
      const u32* pb = pre1 + (size_t)t * 32768 + (size_t)(g * 16 + quad * 4) * 512 + mycol;
#pragma unroll
      for (int j = 0; j < 32; j++)
        v[j] = __hip_atomic_load(rb + (j >> 3) * 512 + (j & 7) * 64,
                                 __ATOMIC_RELAXED, __HIP_MEMORY_SCOPE_AGENT);
#pragma unroll
      for (int i = 0; i < 4; i++)
        p[i] = __hip_atomic_load(pb + i * 512,
                                 __ATOMIC_RELAXED, __HIP_MEMORY_SCOPE_AGENT);
      {
        int guard = 0;
        while (true) {
          u32 pend = 0;
#pragma unroll
          for (int j = 0; j < 32; j++) pend |= ((v[j] >> 16) ^ etag) & 1u;
#pragma unroll
          for (int i = 0; i < 4; i++) pend |= (u32)(p[i] == SENT);
          if (__builtin_expect(pend == 0u, 1)) break;
          if (++guard > (1 << 16)) break;
          __builtin_amdgcn_s_sleep(1);
#pragma unroll
          for (int j = 0; j < 32; j++)
            v[j] = __hip_atomic_load(rb + (j >> 3) * 512 + (j & 7) * 64,
                                     __ATOMIC_RELAXED, __HIP_MEMORY_SCOPE_AGENT);
#pragma unroll
          for (int i = 0; i < 4; i++)
            p[i] = __hip_atomic_load(pb + i * 512,
                                     __ATOMIC_RELAXED, __HIP_MEMORY_SCOPE_AGENT);
        }
      }
#pragma unroll
      for (int rr = 0; rr < 4; rr++) {
        const int row = w4 + rr;
        u32* wrow = &Ab[buf][row][0];
        const int xsw = (row & 7) << 2;
#pragma unroll
        for (int k = 0; k < 8; k++)
          wrow[(k * 64 + lane) ^ xsw] = v[rr * 8 + k];
      }
      __syncthreads();

      floatx4 ac[4];
#pragma unroll
      for (int q = 0; q < 4; q++) ac[q] = (floatx4){0.f, 0.f, 0.f, 0.f};
      const u32* arow = &Ab[buf][l16][0];
#pragma unroll
      for (int s = 0; s < 32; s += 4) {
#pragma unroll
        for (int q = 0; q < 4; q++) {
          bf16x8 a = __builtin_bit_cast(bf16x8,
              *(const u16x8*)(arow + (((s + q) * 16 + quad * 4) ^ xswr)));
          ac[q] = __builtin_amdgcn_mfma_f32_16x16x32_bf16(a, wfh[s + q], ac[q], 0, 0, 0);
        }
      }

      const u32 ntag = (u32)(((t + 1) >> 2) & 1);
#pragma unroll
      for (int i = 0; i < 4; i++) {
        const float vsum = ac[0][i] + ac[1][i] + ac[2][i] + ac[3][i] +
                           __builtin_bit_cast(float, p[i]);
        const float th = fast_tanh(vsum);
        const float nv = (t < lens[i]) ? th : hcur[i];
        hcur[i] = nv;
        const u16 hi = f2bf(nv);
        const u16 lo = f2bf(nv - bf2f(hi));
        u32 wv = (u32)hi | ((u32)lo << 16);
        wv = (wv & 0xFFFEFFFFu) | (ntag << 16);   // tag in lo-bf16 LSB
        __hip_atomic_store(ring1 + (size_t)((t + 1) & 3) * 32768 +
                               (size_t)(g * 16 + quad * 4 + i) * 512 + mycol,
                           wv, __ATOMIC_RELAXED, __HIP_MEMORY_SCOPE_AGENT);
      }
    }
#pragma unroll
    for (int i = 0; i < 4; i++) {
      const int b = g * 16 + quad * 4 + i;
      out[(size_t)b * 512 + mycol] = hcur[i];                    // h_last
      out[32768 + (size_t)b * 1024 + 512 + mycol] = hcur[i];     // hidden[:,1,:]
    }
  }
}

// ---------- sequential recurrence pass (one layer) — FALLBACK only ----------
__global__ __launch_bounds__(256, 1)
void rnn_pass(const u16* __restrict__ Whh, const float* __restrict__ Xpre,
              u32* __restrict__ hist, const int* __restrict__ lengths,
              float* __restrict__ out_last, float* __restrict__ out_hidden) {
  __shared__ u32 Abuf[2][16][512];
  const int tid = threadIdx.x;
  const int wave = tid >> 6, lane = tid & 63;
  const int quad = lane >> 4, l16 = lane & 15;
  const int c = blockIdx.x >> 2, g = blockIdx.x & 3;
  const int mycol = c * 64 + wave * 16 + l16;
  const int w4 = wave * 4;

  bf16x8 wfrag[32];
  {
    const u16* wrow = Whh + (size_t)mycol * 512 + quad * 4;
#pragma unroll
    for (int s = 0; s < 32; s++) {
      u16x4 w4v = *(const u16x4*)(wrow + s * 16);
      u16x8 w8 = {w4v[0], w4v[0], w4v[1], w4v[1], w4v[2], w4v[2], w4v[3], w4v[3]};
      wfrag[s] = __builtin_bit_cast(bf16x8, w8);
    }
  }
  float hcur[4];
  int lens[4];
#pragma unroll
  for (int i = 0; i < 4; i++) {
    hcur[i] = 0.f;
    lens[i] = lengths[g * 16 + quad * 4 + i];
  }
  const int xswr = (l16 & 7) << 2;

  for (int t = 0; t < TT; t++) {
    const int buf = t & 1;
    float pre[4];
#pragma unroll
    for (int i = 0; i < 4; i++)
      pre[i] = Xpre[(size_t)t * 32768 + (size_t)(g * 16 + quad * 4 + i) * 512 + mycol];

    u32 v[32];
    const u32* sbase = hist + (size_t)t * 32768 + (size_t)(g * 16 + w4) * 512 + lane;
#pragma unroll
    for (int j = 0; j < 32; j++)
      v[j] = __hip_atomic_load(sbase + (j >> 3) * 512 + (j & 7) * 64,
                               __ATOMIC_RELAXED, __HIP_MEMORY_SCOPE_AGENT);
    {
      int guard = 0;
      while (true) {
        u32 pend = 0;
#pragma unroll
        for (int j = 0; j < 32; j++) pend |= (u32)(v[j] == SENT);
        if (__builtin_expect(pend == 0u, 1)) break;
        if (++guard > (1 << 16)) break;
        __builtin_amdgcn_s_sleep(1);
#pragma unroll
        for (int j = 0; j < 32; j++)
          v[j] = __hip_atomic_load(sbase + (j >> 3) * 512 + (j & 7) * 64,
                                   __ATOMIC_RELAXED, __HIP_MEMORY_SCOPE_AGENT);
      }
    }
#pragma unroll
    for (int rr = 0; rr < 4; rr++) {
      const int row = w4 + rr;
      u32* wrow = &Abuf[buf][row][0];
      const int xsw = (row & 7) << 2;
#pragma unroll
      for (int k = 0; k < 8; k++)
        wrow[(k * 64 + lane) ^ xsw] = v[rr * 8 + k];
    }
    __syncthreads();

    floatx4 ac[4];
#pragma unroll
    for (int q = 0; q < 4; q++) ac[q] = (floatx4){0.f, 0.f, 0.f, 0.f};
    const u32* arow = &Abuf[buf][l16][0];
#pragma unroll
    for (int s = 0; s < 32; s += 4) {
#pragma unroll
      for (int q = 0; q < 4; q++) {
        bf16x8 a = __builtin_bit_cast(bf16x8,
            *(const u16x8*)(arow + (((s + q) * 16 + quad * 4) ^ xswr)));
        ac[q] = __builtin_amdgcn_mfma_f32_16x16x32_bf16(a, wfrag[s + q], ac[q], 0, 0, 0);
      }
    }

#pragma unroll
    for (int i = 0; i < 4; i++) {
      const float vsum = ac[0][i] + ac[1][i] + ac[2][i] + ac[3][i] + pre[i];
      const float th = fast_tanh(vsum);
      const float nv = (t < lens[i]) ? th : hcur[i];
      hcur[i] = nv;
      const u16 hi = f2bf(nv);
      const u16 lo = f2bf(nv - bf2f(hi));
      u32 wv = (u32)hi | ((u32)lo << 16);
      wv += (wv == SENT);
      __hip_atomic_store(hist + (size_t)(t + 1) * 32768 +
                             (size_t)(g * 16 + quad * 4 + i) * 512 + mycol,
                         wv, __ATOMIC_RELAXED, __HIP_MEMORY_SCOPE_AGENT);
    }
  }
#pragma unroll
  for (int i = 0; i < 4; i++) {
    const int b = g * 16 + quad * 4 + i;
    if (out_hidden) out_hidden[(size_t)b * 1024 + mycol] = hcur[i];
    if (out_last)   out_last[(size_t)b * 512 + mycol] = hcur[i];
  }
}

// ---------- launch ----------
extern "C" void kernel_launch(void* const* d_in, const int* in_sizes, int n_in,
                              void* d_out, int out_size, void* d_ws, size_t ws_size,
                              hipStream_t stream) {
  const int*   x   = (const int*)d_in[0];
  const int*   len = (const int*)d_in[1];
  const float* emb = (const float*)d_in[2];
  const float* Wih = (const float*)d_in[3];
  const float* Whh = (const float*)d_in[4];
  const float* bih = (const float*)d_in[5];
  const float* bhh = (const float*)d_in[6];
  float* out = (float*)d_out;

  char* ws = (char*)d_ws;
  const size_t SZ_XPRE = 67108864;                 // T*B*512 fp32
  const size_t SZ_HIST = 67239936;                 // (T+1)*B*512 u32
  const size_t SZ_PRE1 = 67108864;                 // T*B*512 u32/fp32
  const size_t SZ_RING = 524288;                   // 4 slots * 131072
  const size_t SZ_WBF3 = 1572864;                  // 3 * 512*512 bf16

  const size_t need3 = SZ_XPRE + SZ_HIST + SZ_PRE1 + SZ_RING + SZ_WBF3 + 4096;
  if (ws_size >= need3) {
    // ---------- 3-stage pipelined flow ----------
    float* Xpre  = (float*)(ws);
    u32*   hist0 = (u32*)(ws + SZ_XPRE);
    u32*   pre1  = (u32*)(ws + SZ_XPRE + SZ_HIST);
    u32*   ring1 = (u32*)(ws + SZ_XPRE + SZ_HIST + SZ_PRE1);
    u16*   wbf3  = (u16*)(ws + SZ_XPRE + SZ_HIST + SZ_PRE1 + SZ_RING);
    float* bsum  = (float*)(ws + SZ_XPRE + SZ_HIST + SZ_PRE1 + SZ_RING + SZ_WBF3);

    hipMemsetAsync(hist0, 0, 131072, stream);                               // h0(-1)=0
    hipMemsetAsync((char*)hist0 + 131072, 0xAA, (size_t)512 * 131072, stream); // poison
    hipMemsetAsync(pre1, 0xAA, SZ_PRE1, stream);                            // poison
    hipMemsetAsync(ring1, 0, 131072, stream);                               // h1(-1)=0, tag0
    hipMemsetAsync((char*)ring1 + 131072, 0xFF, 393216, stream);            // slots1-3: tag1
    hipLaunchKernelGGL(prep_kernel, dim3(512), dim3(256), 0, stream, Wih, Whh, bih, bhh, wbf3, bsum);
    hipLaunchKernelGGL(gemm_pre, dim3(1024), dim3(256), 0, stream,
                       Wih /*fp32 wih0*/, bsum, emb, x, (const u32*)nullptr, Xpre, 0);
    hipLaunchKernelGGL(rnn_fused3, dim3(96), dim3(256), 0, stream,
                       wbf3, bsum, Xpre, hist0, pre1, ring1, len, out);
  } else {
    // ---------- fallback: proven sequential two-pass flow ----------
    float* Xpre  = (float*)(ws);
    u32*   hist  = (u32*)(ws + SZ_XPRE);
    u16*   wbf3  = (u16*)(ws + SZ_XPRE + SZ_HIST);
    float* bsum  = (float*)(ws + SZ_XPRE + SZ_HIST + SZ_WBF3);

    hipMemsetAsync(hist, 0, 131072, stream);
    hipMemsetAsync((char*)hist + 131072, 0xAA, (size_t)512 * 131072, stream);
    hipLaunchKernelGGL(prep_kernel, dim3(512), dim3(256), 0, stream, Wih, Whh, bih, bhh, wbf3, bsum);
    hipLaunchKernelGGL(gemm_pre, dim3(1024), dim3(256), 0, stream,
                       Wih /*fp32 wih0*/, bsum, emb, x, (const u32*)nullptr, Xpre, 0);
    hipLaunchKernelGGL(rnn_pass, dim3(32), dim3(256), 0, stream,
                       wbf3 /*whh0*/, Xpre, hist, len,
                       (float*)nullptr, out + 32768);
    hipLaunchKernelGGL(gemm_pre, dim3(1024), dim3(256), 0, stream,
                       Wih + 262144 /*fp32 wih1*/, bsum + 512, (const float*)nullptr, (const int*)nullptr,
                       hist, Xpre, 1);
    hipMemsetAsync((char*)hist + 131072, 0xAA, (size_t)512 * 131072, stream);
    hipLaunchKernelGGL(rnn_pass, dim3(32), dim3(256), 0, stream,
                       wbf3 + 524288 /*whh1*/, Xpre, hist, len,
                       out, out + 32768 + 512);
  }
}